// Round 2
// baseline (15524.890 us; speedup 1.0000x reference)
//
#include <hip/hip_runtime.h>

#define BB 64
#define TT 512
#define EE 512
#define RR 2048
#define NWG 64
#define CPW 32   // columns per scan workgroup

typedef _Float16 f16;
typedef f16 f16x8 __attribute__((ext_vector_type(8)));
typedef float f32x4 __attribute__((ext_vector_type(4)));

__device__ __forceinline__ void gload16(const void* g, void* l) {
  __builtin_amdgcn_global_load_lds(
      (const __attribute__((address_space(1))) void*)g,
      (__attribute__((address_space(3))) void*)l, 16, 0, 0);
}

__device__ __forceinline__ float fast_tanh(float v) {
  float e = __expf(2.0f * v);
  return 1.0f - 2.0f / (e + 1.0f);
}

// device-coherent (cross-XCD) 16B load of previous state: two relaxed
// agent-scope 8B atomic loads -> global_load_dwordx2 with device-scope
// cache bits (bypass stale L1/L2, read from L3) and NO fence.
__device__ __forceinline__ f16x8 loadA16(const f16* p) {
  union { f16x8 v; unsigned long long q[2]; } u;
  unsigned long long* a = (unsigned long long*)p;
  u.q[0] = __hip_atomic_load(a,     __ATOMIC_RELAXED, __HIP_MEMORY_SCOPE_AGENT);
  u.q[1] = __hip_atomic_load(a + 1, __ATOMIC_RELAXED, __HIP_MEMORY_SCOPE_AGENT);
  return u.v;
}

// device-coherent 2B store of next state (write-through past local L2)
__device__ __forceinline__ void storeS(f16* p, float v) {
  union { f16 h; unsigned short s; } u;
  u.h = (f16)v;
  __hip_atomic_store((unsigned short*)p, u.s, __ATOMIC_RELAXED, __HIP_MEMORY_SCOPE_AGENT);
}

// ---------------- prep kernels ----------------

__global__ void prep_emb(const int* __restrict__ x, const float* __restrict__ ew,
                         f16* __restrict__ emb) {
  const int row = blockIdx.x;            // token index 0..32767 (b*T + t)
  const int tok = x[row];
  const float4* src = (const float4*)(ew + (size_t)tok * EE);
  f16* dst = emb + (size_t)row * EE;
  const int i = threadIdx.x;             // 128 threads, 4 f16 each
  float4 v = src[i];
  union { f16 h[4]; unsigned long long u; } p;
  p.h[0] = (f16)v.x; p.h[1] = (f16)v.y; p.h[2] = (f16)v.z; p.h[3] = (f16)v.w;
  ((unsigned long long*)dst)[i] = p.u;
}

__global__ void prep_winT(const float* __restrict__ Win, f16* __restrict__ WinT) {
  const int i = blockIdx.x * blockDim.x + threadIdx.x;  // over EE*RR
  if (i < EE * RR) {
    const int k = i / RR, n = i % RR;
    WinT[(size_t)n * EE + k] = (f16)Win[i];
  }
}

// ---------------- projection GEMM: U[t][b][n] = emb[b,t,:] @ Win[:,n] ----------------

__launch_bounds__(256, 1)
__global__ void proj_gemm(const f16* __restrict__ A, const f16* __restrict__ Bt,
                          float* __restrict__ U) {
  __shared__ f16 As[128 * 32];
  __shared__ f16 Bs[128 * 32];
  const int tid = threadIdx.x;
  const int wv = tid >> 6, l = tid & 63;
  const int m0 = blockIdx.x * 128, n0 = blockIdx.y * 128;
  const int wm = wv >> 1, wn = wv & 1;
  const int srow = tid >> 2, sc = tid & 3;
  const int r = l & 15, kb = l >> 4;
  f32x4 acc[4][4] = {};

  for (int k0 = 0; k0 < EE; k0 += 32) {
    __syncthreads();
#pragma unroll
    for (int q = 0; q < 2; ++q) {
      const int row = q * 64 + srow;
      const int cc = sc ^ (row & 3);   // source pre-swizzle -> swizzled linear LDS
      gload16(A + (size_t)(m0 + row) * EE + k0 + cc * 8,
              (char*)As + q * 4096 + wv * 1024);
      gload16(Bt + (size_t)(n0 + row) * EE + k0 + cc * 8,
              (char*)Bs + q * 4096 + wv * 1024);
    }
    __syncthreads();
    f16x8 af[4], bf[4];
#pragma unroll
    for (int mi = 0; mi < 4; ++mi) {
      const int row = wm * 64 + mi * 16 + r;
      af[mi] = *(const f16x8*)&As[row * 32 + ((kb ^ (row & 3)) * 8)];
    }
#pragma unroll
    for (int ni = 0; ni < 4; ++ni) {
      const int row = wn * 64 + ni * 16 + r;
      bf[ni] = *(const f16x8*)&Bs[row * 32 + ((kb ^ (row & 3)) * 8)];
    }
#pragma unroll
    for (int mi = 0; mi < 4; ++mi)
#pragma unroll
      for (int ni = 0; ni < 4; ++ni)
        acc[mi][ni] = __builtin_amdgcn_mfma_f32_16x16x32_f16(af[mi], bf[ni], acc[mi][ni], 0, 0, 0);
  }
  const int rb = kb * 4;
#pragma unroll
  for (int mi = 0; mi < 4; ++mi)
#pragma unroll
    for (int ni = 0; ni < 4; ++ni)
#pragma unroll
      for (int j = 0; j < 4; ++j) {
        const int m = m0 + wm * 64 + mi * 16 + rb + j;   // token index (b*512 + t)
        const int n = n0 + wn * 64 + ni * 16 + r;
        const int b = m >> 9, t = m & 511;
        // non-temporal: U is a 256 MB write-once stream; keep it out of L3's way
        __builtin_nontemporal_store(acc[mi][ni][j], &U[(size_t)(t * BB + b) * RR + n]);
      }
}

// ---------------- the sequential reservoir scan ----------------

// fence-free global barrier: data coherence is carried by the sc-flagged
// S loads/stores themselves; the flag only needs relaxed atomicity.
// __syncthreads drains vmcnt(0), so all S stores are at the coherence
// point before the flag increment.
__device__ __forceinline__ void gbar(unsigned* bar, int t, int tid) {
  __syncthreads();
  if (tid == 0) {
    __hip_atomic_fetch_add(&bar[t], 1u, __ATOMIC_RELAXED, __HIP_MEMORY_SCOPE_AGENT);
    while (__hip_atomic_load(&bar[t], __ATOMIC_RELAXED, __HIP_MEMORY_SCOPE_AGENT) < NWG)
      __builtin_amdgcn_s_sleep(4);
  }
  __syncthreads();
  // compiler-level ordering only (workgroup scope): no L2 writeback/invalidate
  __builtin_amdgcn_fence(__ATOMIC_ACQUIRE, "workgroup");
}

__launch_bounds__(512, 1)
__global__ void scan_kernel(const float* __restrict__ R, const float* __restrict__ U,
                            f16* __restrict__ S, unsigned* __restrict__ bar) {
  __shared__ f16 Rt[CPW * RR];   // 32 cols x 2048 rows, transposed [n][k], 128 KB
  const int g = blockIdx.x;
  const int tid = threadIdx.x;
  const int nbase = g * CPW;

  // prologue: load this WG's R column slice, transpose + XOR-swizzle into LDS
  {
    const int cidx = tid & 31;     // column within slice
    const int kst = tid >> 5;      // 0..15
    const int sw = (cidx & 7) << 3;
    for (int k = kst; k < RR; k += 16) {
      float v = R[(size_t)k * RR + nbase + cidx];
      Rt[(cidx * RR + k) ^ sw] = (f16)v;
    }
  }

  // step 0: state0 = 0 -> state1 = tanh(u0); write own column slice
  for (int i = tid; i < BB * CPW; i += 512) {
    const int m = i >> 5, cl = i & 31;
    storeS(&S[(size_t)m * RR + nbase + cl],
           fast_tanh(__builtin_nontemporal_load(&U[(size_t)m * RR + nbase + cl])));
  }

  const int wv = tid >> 6, l = tid & 63;
  const int mt = wv >> 1, nt = wv & 1;      // 4 m-tiles x 2 n-tiles = 8 waves
  const int r = l & 15, kb = l >> 4;
  const int mrow = mt * 16 + r;             // A row (batch)
  const int nl = nt * 16 + r;               // B col within slice
  const int bsw = (nl & 7) << 3;
  const int belem0 = nl * RR + kb * 8;
  const int coln = nbase + nt * 16 + r;     // D col (global)
  const int rb = kb * 4;

  // prefetch u_1 before the barrier; HBM latency hides under barrier wait
  float ucur[4];
#pragma unroll
  for (int j = 0; j < 4; ++j)
    ucur[j] = __builtin_nontemporal_load(
        &U[(size_t)1 * (BB * RR) + (size_t)(mt * 16 + rb + j) * RR + coln]);

  gbar(bar, 0, tid);

  for (int t = 1; t < TT; ++t) {
    const f16* Sprev = S + (size_t)((t + 1) & 1) * (BB * RR);
    f16* Snext = S + (size_t)(t & 1) * (BB * RR);
    const f16* arow = Sprev + (size_t)mrow * RR + kb * 8;
    f32x4 acc = {0.f, 0.f, 0.f, 0.f};
#pragma unroll 16
    for (int k0 = 0; k0 < RR; k0 += 32) {
      f16x8 a = loadA16(arow + k0);
      f16x8 b = *(const f16x8*)&Rt[(belem0 + k0) ^ bsw];
      acc = __builtin_amdgcn_mfma_f32_16x16x32_f16(a, b, acc, 0, 0, 0);
    }
    // prefetch u_{t+1}; drains to registers during the barrier spin
    const int tn = (t + 1 < TT) ? t + 1 : t;
    float unxt[4];
#pragma unroll
    for (int j = 0; j < 4; ++j)
      unxt[j] = __builtin_nontemporal_load(
          &U[(size_t)tn * (BB * RR) + (size_t)(mt * 16 + rb + j) * RR + coln]);
#pragma unroll
    for (int j = 0; j < 4; ++j) {
      const int m = mt * 16 + rb + j;
      storeS(&Snext[(size_t)m * RR + coln], fast_tanh(acc[j] + ucur[j]));
    }
    if (t + 1 < TT) gbar(bar, t, tid);
#pragma unroll
    for (int j = 0; j < 4; ++j) ucur[j] = unxt[j];
  }
}

// ---------------- LayerNorm ----------------

__launch_bounds__(256, 1)
__global__ void ln_kernel(const f16* __restrict__ Sfin, const float* __restrict__ gamma,
                          const float* __restrict__ beta, float* __restrict__ out) {
  const int b = blockIdx.x;
  const int tid = threadIdx.x;
  const f16* row = Sfin + (size_t)b * RR;
  float vals[8];
  float lsum = 0.f, lsq = 0.f;
#pragma unroll
  for (int i = 0; i < 8; ++i) {
    float v = (float)row[tid + i * 256];
    vals[i] = v; lsum += v; lsq += v * v;
  }
#pragma unroll
  for (int off = 32; off >= 1; off >>= 1) {
    lsum += __shfl_xor(lsum, off);
    lsq  += __shfl_xor(lsq, off);
  }
  __shared__ float ps[4], pq[4];
  __shared__ float mu_s, rstd_s;
  const int wv = tid >> 6, l = tid & 63;
  if (l == 0) { ps[wv] = lsum; pq[wv] = lsq; }
  __syncthreads();
  if (tid == 0) {
    float s = 0.f, q = 0.f;
    for (int i = 0; i < 4; ++i) { s += ps[i]; q += pq[i]; }
    const float mu = s / RR;
    const float var = q / RR - mu * mu;
    mu_s = mu; rstd_s = rsqrtf(var + 1e-5f);
  }
  __syncthreads();
  const float mu = mu_s, rstd = rstd_s;
#pragma unroll
  for (int i = 0; i < 8; ++i) {
    const int idx = tid + i * 256;
    out[(size_t)b * RR + idx] = (vals[i] - mu) * rstd * gamma[idx] + beta[idx];
  }
}

// ---------------- launch ----------------

extern "C" void kernel_launch(void* const* d_in, const int* in_sizes, int n_in,
                              void* d_out, int out_size, void* d_ws, size_t ws_size,
                              hipStream_t stream) {
  const int*   x     = (const int*)d_in[0];
  const float* ew    = (const float*)d_in[1];
  const float* Rm    = (const float*)d_in[2];
  const float* Win   = (const float*)d_in[3];
  const float* gamma = (const float*)d_in[4];
  const float* beta  = (const float*)d_in[5];

  const size_t U_OFF   = 0;                           // fp32  512*64*2048*4 = 268435456
  const size_t EMB_OFF = 268435456;                   // fp16  32768*512*2   =  33554432
  const size_t WT_OFF  = EMB_OFF + 33554432;          // fp16  2048*512*2    =   2097152
  const size_t S_OFF   = WT_OFF + 2097152;            // fp16  2*64*2048*2   =    524288
  const size_t BAR_OFF = S_OFF + 524288;              // u32   512*4
  const size_t NEED    = BAR_OFF + 2048;
  if (ws_size < NEED) {   // signal: leave output zeroed (distinctive absmax)
    hipMemsetAsync(d_out, 0, (size_t)out_size * 4, stream);
    return;
  }
  char* ws = (char*)d_ws;
  float*    Ubuf = (float*)(ws + U_OFF);
  f16*      emb  = (f16*)(ws + EMB_OFF);
  f16*      WinT = (f16*)(ws + WT_OFF);
  f16*      Sbuf = (f16*)(ws + S_OFF);
  unsigned* bar  = (unsigned*)(ws + BAR_OFF);

  hipMemsetAsync(bar, 0, TT * sizeof(unsigned), stream);
  prep_emb<<<BB * TT, 128, 0, stream>>>(x, ew, emb);
  prep_winT<<<(EE * RR) / 256, 256, 0, stream>>>(Win, WinT);
  proj_gemm<<<dim3((BB * TT) / 128, RR / 128), 256, 0, stream>>>(emb, WinT, Ubuf);
  scan_kernel<<<NWG, 512, 0, stream>>>(Rm, Ubuf, Sbuf, bar);
  ln_kernel<<<BB, 256, 0, stream>>>(Sbuf + (size_t)BB * RR, gamma, beta, (float*)d_out);
}

// Round 3
// 8940.311 us; speedup vs baseline: 1.7365x; 1.7365x over previous
//
#include <hip/hip_runtime.h>

#define BB 64
#define TT 512
#define EE 512
#define RR 2048
#define NWG 64
#define CPW 32   // columns per scan workgroup

typedef _Float16 f16;
typedef f16 f16x8 __attribute__((ext_vector_type(8)));
typedef float f32x4 __attribute__((ext_vector_type(4)));

__device__ __forceinline__ void gload16(const void* g, void* l) {
  __builtin_amdgcn_global_load_lds(
      (const __attribute__((address_space(1))) void*)g,
      (__attribute__((address_space(3))) void*)l, 16, 0, 0);
}

__device__ __forceinline__ float fast_tanh(float v) {
  float e = __expf(2.0f * v);
  return 1.0f - 2.0f / (e + 1.0f);
}

// write-through device-coherent 2B store (proven in R2)
__device__ __forceinline__ void storeS(f16* p, float v) {
  union { f16 h; unsigned short s; } u;
  u.h = (f16)v;
  __hip_atomic_store((unsigned short*)p, u.s, __ATOMIC_RELAXED, __HIP_MEMORY_SCOPE_AGENT);
}

__device__ __forceinline__ unsigned flag_ld(const unsigned* p) {
  return __hip_atomic_load(p, __ATOMIC_RELAXED, __HIP_MEMORY_SCOPE_AGENT);
}
__device__ __forceinline__ void flag_st(unsigned* p, unsigned v) {
  __hip_atomic_store(p, v, __ATOMIC_RELAXED, __HIP_MEMORY_SCOPE_AGENT);
}

// batch of 8 device-coherent 16B loads, literal imm offsets BASE..BASE+448 bytes
template <int BASE>
__device__ __forceinline__ void issue8(f16x8* dst, unsigned voff, const f16* sbase) {
#pragma unroll
  for (int i = 0; i < 8; ++i)
    asm volatile("global_load_dwordx4 %0, %1, %2 offset:%c3 sc0 sc1"
                 : "=v"(dst[i]) : "v"(voff), "s"(sbase), "i"(BASE + 64 * i) : "memory");
}

template <int N>
__device__ __forceinline__ void wait_vm() {
  asm volatile("s_waitcnt vmcnt(%c0)" :: "i"(N) : "memory");
  __builtin_amdgcn_sched_barrier(0);   // rule #18: pin uses after the wait
}

// ---------------- prep kernels ----------------

__global__ void prep_emb(const int* __restrict__ x, const float* __restrict__ ew,
                         f16* __restrict__ emb) {
  const int row = blockIdx.x;            // token index (b*T + t)
  const int tok = x[row];
  const float4* src = (const float4*)(ew + (size_t)tok * EE);
  f16* dst = emb + (size_t)row * EE;
  const int i = threadIdx.x;             // 128 threads, 4 f16 each
  float4 v = src[i];
  union { f16 h[4]; unsigned long long u; } p;
  p.h[0] = (f16)v.x; p.h[1] = (f16)v.y; p.h[2] = (f16)v.z; p.h[3] = (f16)v.w;
  ((unsigned long long*)dst)[i] = p.u;
}

__global__ void prep_winT(const float* __restrict__ Win, f16* __restrict__ WinT) {
  const int i = blockIdx.x * blockDim.x + threadIdx.x;  // over EE*RR
  if (i < EE * RR) {
    const int k = i / RR, n = i % RR;
    WinT[(size_t)n * EE + k] = (f16)Win[i];
  }
}

// ---------------- projection GEMM: U[t][b][n] = emb[b,t,:] @ Win[:,n] ----------------

__launch_bounds__(256, 1)
__global__ void proj_gemm(const f16* __restrict__ A, const f16* __restrict__ Bt,
                          float* __restrict__ U) {
  __shared__ f16 As[128 * 32];
  __shared__ f16 Bs[128 * 32];
  const int tid = threadIdx.x;
  const int wv = tid >> 6, l = tid & 63;
  const int m0 = blockIdx.x * 128, n0 = blockIdx.y * 128;
  const int wm = wv >> 1, wn = wv & 1;
  const int srow = tid >> 2, sc = tid & 3;
  const int r = l & 15, kb = l >> 4;
  f32x4 acc[4][4] = {};

  for (int k0 = 0; k0 < EE; k0 += 32) {
    __syncthreads();
#pragma unroll
    for (int q = 0; q < 2; ++q) {
      const int row = q * 64 + srow;
      const int cc = sc ^ (row & 3);
      gload16(A + (size_t)(m0 + row) * EE + k0 + cc * 8,
              (char*)As + q * 4096 + wv * 1024);
      gload16(Bt + (size_t)(n0 + row) * EE + k0 + cc * 8,
              (char*)Bs + q * 4096 + wv * 1024);
    }
    __syncthreads();
    f16x8 af[4], bf[4];
#pragma unroll
    for (int mi = 0; mi < 4; ++mi) {
      const int row = wm * 64 + mi * 16 + r;
      af[mi] = *(const f16x8*)&As[row * 32 + ((kb ^ (row & 3)) * 8)];
    }
#pragma unroll
    for (int ni = 0; ni < 4; ++ni) {
      const int row = wn * 64 + ni * 16 + r;
      bf[ni] = *(const f16x8*)&Bs[row * 32 + ((kb ^ (row & 3)) * 8)];
    }
#pragma unroll
    for (int mi = 0; mi < 4; ++mi)
#pragma unroll
      for (int ni = 0; ni < 4; ++ni)
        acc[mi][ni] = __builtin_amdgcn_mfma_f32_16x16x32_f16(af[mi], bf[ni], acc[mi][ni], 0, 0, 0);
  }
  const int rb = kb * 4;
#pragma unroll
  for (int mi = 0; mi < 4; ++mi)
#pragma unroll
    for (int ni = 0; ni < 4; ++ni)
#pragma unroll
      for (int j = 0; j < 4; ++j) {
        const int m = m0 + wm * 64 + mi * 16 + rb + j;   // token index (b*512 + t)
        const int n = n0 + wn * 64 + ni * 16 + r;
        const int b = m >> 9, t = m & 511;
        __builtin_nontemporal_store(acc[mi][ni][j], &U[(size_t)(t * BB + b) * RR + n]);
      }
}

// ---------------- the sequential reservoir scan (dataflow, no fences) ----------------
// state_tau (tau=1..512) lives at instance tau&1. flag[g]=tau after WG g's
// 32-column chunk of state_tau is at the coherence point (L3).
// All S reads are sc0/sc1 bypass loads -> L1/L2 never hold S lines -> no
// invalidates needed anywhere. All S writes are write-through (R2-proven).

__launch_bounds__(512, 1)
__global__ void scan_kernel(const float* __restrict__ R, const float* __restrict__ U,
                            f16* __restrict__ S, unsigned* __restrict__ flg) {
  // LDS layout: chunk (kt=k>>5, nt=c>>4, id=(c&15)*4 + ((k>>3)&3)) of 16B:
  // byte = kt*2048 + nt*1024 + id*16 + (k&7)*2  -> each wave's B-fragment
  // read is 1024 contiguous bytes => zero bank conflicts.
  __shared__ f16 Rt[CPW * RR];   // 128 KB
  const int g = blockIdx.x, tid = threadIdx.x;
  const int nbase = g * CPW;

  // tau = 1: state_1 = tanh(u_0); write own chunk early, publish flag
  for (int i = tid; i < BB * CPW; i += 512) {
    const int m = i >> 5, cl = i & 31;
    storeS(&S[(size_t)(BB * RR) + (size_t)m * RR + nbase + cl],
           fast_tanh(U[(size_t)m * RR + nbase + cl]));
  }
  __syncthreads();
  if (tid == 0) flag_st(&flg[g], 1u);

  // R column slice -> LDS (chunked layout); conflicts here are once-only
  {
    const int c = tid & 31, kst = tid >> 5;
    for (int k = kst; k < RR; k += 16) {
      const float v = R[(size_t)k * RR + nbase + c];
      const int idx = ((k >> 5) << 10) + ((c >> 4) << 9) +
                      (((c & 15) << 2) + ((k >> 3) & 3)) * 8 + (k & 7);
      Rt[idx] = (f16)v;
    }
  }
  __syncthreads();

  const int wv = tid >> 6, l = tid & 63;
  const int mt = wv >> 1, nt = wv & 1;      // 4 m-tiles x 2 n-tiles
  const int r = l & 15, kb = l >> 4;
  const int rb = kb * 4;
  const int coln = nbase + nt * 16 + r;
  const char* RtB = (const char*)Rt;
  const int bbyte = nt * 1024 + (r * 4 + kb) * 16;
  const unsigned voffA = (unsigned)(((mt * 16 + r) * RR + kb * 8) * 2);
  const int fl = l & 7;

  f16x8 abuf[2][8];

  for (int tau = 2; tau <= TT; ++tau) {
    const f16* sprevp = S + (size_t)((tau - 1) & 1) * (BB * RR);
    f16* snextp = S + (size_t)(tau & 1) * (BB * RR);
    const float* uptr = U + (size_t)(tau - 1) * (BB * RR);
    const unsigned need = (unsigned)(tau - 1);
    f32x4 acc = {0.f, 0.f, 0.f, 0.f};
    float uc[4];

    // one 64-flag check; its result-wait has nothing else outstanding
    unsigned fv0 = flag_ld(&flg[l]);
    if (__all(fv0 >= need)) {
      // -------- fast path: fully pipelined, 2-deep batch double-buffer ----
#pragma unroll
      for (int j = 0; j < 4; ++j) {
        const unsigned uoff = (unsigned)((((mt * 16 + rb + j) * RR) + coln) * 4);
        asm volatile("global_load_dword %0, %1, %2"
                     : "=v"(uc[j]) : "v"(uoff), "s"(uptr) : "memory");
      }
      issue8<0>(abuf[0], voffA, sprevp);
      issue8<512>(abuf[1], voffA, sprevp);
#define COMP8(BQ, BI)                                                          \
  _Pragma("unroll") for (int i = 0; i < 8; ++i) {                              \
    f16x8 bfr = *(const f16x8*)(RtB + ((BI) * 8 + i) * 2048 + bbyte);          \
    acc = __builtin_amdgcn_mfma_f32_16x16x32_f16(abuf[BQ][i], bfr, acc, 0, 0, 0); \
  }
      wait_vm<8>(); COMP8(0, 0); issue8<1024>(abuf[0], voffA, sprevp);
      wait_vm<8>(); COMP8(1, 1); issue8<1536>(abuf[1], voffA, sprevp);
      wait_vm<8>(); COMP8(0, 2); issue8<2048>(abuf[0], voffA, sprevp);
      wait_vm<8>(); COMP8(1, 3); issue8<2560>(abuf[1], voffA, sprevp);
      wait_vm<8>(); COMP8(0, 4); issue8<3072>(abuf[0], voffA, sprevp);
      wait_vm<8>(); COMP8(1, 5); issue8<3584>(abuf[1], voffA, sprevp);
      wait_vm<8>(); COMP8(0, 6);
      wait_vm<0>(); COMP8(1, 7);
    } else {
      // -------- slow path: poll per 8-chunk group, same k-order (bit-identical)
#pragma unroll
      for (int j = 0; j < 4; ++j) {
        const unsigned uoff = (unsigned)((((mt * 16 + rb + j) * RR) + coln) * 4);
        asm volatile("global_load_dword %0, %1, %2"
                     : "=v"(uc[j]) : "v"(uoff), "s"(uptr) : "memory");
      }
      for (int gi = 0; gi < 8; ++gi) {
        unsigned fv = flag_ld(&flg[gi * 8 + fl]);
        while (!__all(fv >= need)) {
          __builtin_amdgcn_s_sleep(1);
          fv = flag_ld(&flg[gi * 8 + fl]);
        }
        const unsigned vg = voffA + (unsigned)(gi * 512);
        issue8<0>(abuf[0], vg, sprevp);
        wait_vm<0>();
#pragma unroll
        for (int i = 0; i < 8; ++i) {
          f16x8 bfr = *(const f16x8*)(RtB + (gi * 8 + i) * 2048 + bbyte);
          acc = __builtin_amdgcn_mfma_f32_16x16x32_f16(abuf[0][i], bfr, acc, 0, 0, 0);
        }
      }
    }

#pragma unroll
    for (int j = 0; j < 4; ++j)
      storeS(&snextp[(size_t)(mt * 16 + rb + j) * RR + coln],
             fast_tanh(acc[j] + uc[j]));
    __syncthreads();                       // drains all waves' stores
    if (tid == 0) flag_st(&flg[g], (unsigned)tau);
  }
}

// ---------------- LayerNorm ----------------

__launch_bounds__(256, 1)
__global__ void ln_kernel(const f16* __restrict__ Sfin, const float* __restrict__ gamma,
                          const float* __restrict__ beta, float* __restrict__ out) {
  const int b = blockIdx.x;
  const int tid = threadIdx.x;
  const f16* row = Sfin + (size_t)b * RR;
  float vals[8];
  float lsum = 0.f, lsq = 0.f;
#pragma unroll
  for (int i = 0; i < 8; ++i) {
    float v = (float)row[tid + i * 256];
    vals[i] = v; lsum += v; lsq += v * v;
  }
#pragma unroll
  for (int off = 32; off >= 1; off >>= 1) {
    lsum += __shfl_xor(lsum, off);
    lsq  += __shfl_xor(lsq, off);
  }
  __shared__ float ps[4], pq[4];
  __shared__ float mu_s, rstd_s;
  const int wv = tid >> 6, l = tid & 63;
  if (l == 0) { ps[wv] = lsum; pq[wv] = lsq; }
  __syncthreads();
  if (tid == 0) {
    float s = 0.f, q = 0.f;
    for (int i = 0; i < 4; ++i) { s += ps[i]; q += pq[i]; }
    const float mu = s / RR;
    const float var = q / RR - mu * mu;
    mu_s = mu; rstd_s = rsqrtf(var + 1e-5f);
  }
  __syncthreads();
  const float mu = mu_s, rstd = rstd_s;
#pragma unroll
  for (int i = 0; i < 8; ++i) {
    const int idx = tid + i * 256;
    out[(size_t)b * RR + idx] = (vals[i] - mu) * rstd * gamma[idx] + beta[idx];
  }
}

// ---------------- launch ----------------

extern "C" void kernel_launch(void* const* d_in, const int* in_sizes, int n_in,
                              void* d_out, int out_size, void* d_ws, size_t ws_size,
                              hipStream_t stream) {
  const int*   x     = (const int*)d_in[0];
  const float* ew    = (const float*)d_in[1];
  const float* Rm    = (const float*)d_in[2];
  const float* Win   = (const float*)d_in[3];
  const float* gamma = (const float*)d_in[4];
  const float* beta  = (const float*)d_in[5];

  const size_t U_OFF   = 0;                           // fp32  512*64*2048*4
  const size_t EMB_OFF = 268435456;                   // fp16  32768*512*2
  const size_t WT_OFF  = EMB_OFF + 33554432;          // fp16  2048*512*2
  const size_t S_OFF   = WT_OFF + 2097152;            // fp16  2*64*2048*2
  const size_t BAR_OFF = S_OFF + 524288;              // u32   64 flags
  const size_t NEED    = BAR_OFF + 2048;
  if (ws_size < NEED) {
    hipMemsetAsync(d_out, 0, (size_t)out_size * 4, stream);
    return;
  }
  char* ws = (char*)d_ws;
  float*    Ubuf = (float*)(ws + U_OFF);
  f16*      emb  = (f16*)(ws + EMB_OFF);
  f16*      WinT = (f16*)(ws + WT_OFF);
  f16*      Sbuf = (f16*)(ws + S_OFF);
  unsigned* flg  = (unsigned*)(ws + BAR_OFF);

  hipMemsetAsync(flg, 0, NWG * sizeof(unsigned), stream);
  prep_emb<<<BB * TT, 128, 0, stream>>>(x, ew, emb);
  prep_winT<<<(EE * RR) / 256, 256, 0, stream>>>(Win, WinT);
  proj_gemm<<<dim3((BB * TT) / 128, RR / 128), 256, 0, stream>>>(emb, WinT, Ubuf);
  scan_kernel<<<NWG, 512, 0, stream>>>(Rm, Ubuf, Sbuf, flg);
  // state_512 lives at instance 512&1 == 0
  ln_kernel<<<BB, 256, 0, stream>>>(Sbuf, gamma, beta, (float*)d_out);
}

// Round 4
// 4079.104 us; speedup vs baseline: 3.8060x; 2.1917x over previous
//
#include <hip/hip_runtime.h>

#define BB 64
#define TT 512
#define EE 512
#define RR 2048
#define CPW 32    // columns per scan workgroup
#define RPG 16    // rows (batch) per group
#define NWGS 256  // 4 groups x 64 col-WGs

typedef _Float16 f16;
typedef f16 f16x8 __attribute__((ext_vector_type(8)));
typedef float f32x4 __attribute__((ext_vector_type(4)));

__device__ __forceinline__ void gload16(const void* g, void* l) {
  __builtin_amdgcn_global_load_lds(
      (const __attribute__((address_space(1))) void*)g,
      (__attribute__((address_space(3))) void*)l, 16, 0, 0);
}

__device__ __forceinline__ float fast_tanh(float v) {
  float e = __expf(2.0f * v);
  return 1.0f - 2.0f / (e + 1.0f);
}

// write-through device-coherent 2B store (R2/R3-proven)
__device__ __forceinline__ void storeS(f16* p, float v) {
  union { f16 h; unsigned short s; } u;
  u.h = (f16)v;
  __hip_atomic_store((unsigned short*)p, u.s, __ATOMIC_RELAXED, __HIP_MEMORY_SCOPE_AGENT);
}

__device__ __forceinline__ unsigned flag_ld(const unsigned* p) {
  return __hip_atomic_load(p, __ATOMIC_RELAXED, __HIP_MEMORY_SCOPE_AGENT);
}
__device__ __forceinline__ void flag_st(unsigned* p, unsigned v) {
  __hip_atomic_store(p, v, __ATOMIC_RELAXED, __HIP_MEMORY_SCOPE_AGENT);
}

// batch of 8 device-coherent 16B loads, imm offsets 0..448 (= ks*64 bytes)
__device__ __forceinline__ void issue8(f16x8* dst, unsigned voff, const f16* sbase) {
#pragma unroll
  for (int i = 0; i < 8; ++i)
    asm volatile("global_load_dwordx4 %0, %1, %2 offset:%c3 sc0 sc1"
                 : "=v"(dst[i]) : "v"(voff), "s"(sbase), "i"(64 * i) : "memory");
}

template <int N>
__device__ __forceinline__ void wait_vm() {
  asm volatile("s_waitcnt vmcnt(%c0)" :: "i"(N) : "memory");
  __builtin_amdgcn_sched_barrier(0);   // rule #18
}

// ---------------- prep kernels ----------------

__global__ void prep_emb(const int* __restrict__ x, const float* __restrict__ ew,
                         f16* __restrict__ emb) {
  const int row = blockIdx.x;            // token index (b*T + t)
  const int tok = x[row];
  const float4* src = (const float4*)(ew + (size_t)tok * EE);
  f16* dst = emb + (size_t)row * EE;
  const int i = threadIdx.x;             // 128 threads, 4 f16 each
  float4 v = src[i];
  union { f16 h[4]; unsigned long long u; } p;
  p.h[0] = (f16)v.x; p.h[1] = (f16)v.y; p.h[2] = (f16)v.z; p.h[3] = (f16)v.w;
  ((unsigned long long*)dst)[i] = p.u;
}

__global__ void prep_winT(const float* __restrict__ Win, f16* __restrict__ WinT) {
  const int i = blockIdx.x * blockDim.x + threadIdx.x;  // over EE*RR
  if (i < EE * RR) {
    const int k = i / RR, n = i % RR;
    WinT[(size_t)n * EE + k] = (f16)Win[i];
  }
}

// ---------------- projection GEMM: U[t][b][n] = emb[b,t,:] @ Win[:,n] ----------------

__launch_bounds__(256, 1)
__global__ void proj_gemm(const f16* __restrict__ A, const f16* __restrict__ Bt,
                          float* __restrict__ U) {
  __shared__ f16 As[128 * 32];
  __shared__ f16 Bs[128 * 32];
  const int tid = threadIdx.x;
  const int wv = tid >> 6, l = tid & 63;
  const int m0 = blockIdx.x * 128, n0 = blockIdx.y * 128;
  const int wm = wv >> 1, wn = wv & 1;
  const int srow = tid >> 2, sc = tid & 3;
  const int r = l & 15, kb = l >> 4;
  f32x4 acc[4][4] = {};

  for (int k0 = 0; k0 < EE; k0 += 32) {
    __syncthreads();
#pragma unroll
    for (int q = 0; q < 2; ++q) {
      const int row = q * 64 + srow;
      const int cc = sc ^ (row & 3);
      gload16(A + (size_t)(m0 + row) * EE + k0 + cc * 8,
              (char*)As + q * 4096 + wv * 1024);
      gload16(Bt + (size_t)(n0 + row) * EE + k0 + cc * 8,
              (char*)Bs + q * 4096 + wv * 1024);
    }
    __syncthreads();
    f16x8 af[4], bf[4];
#pragma unroll
    for (int mi = 0; mi < 4; ++mi) {
      const int row = wm * 64 + mi * 16 + r;
      af[mi] = *(const f16x8*)&As[row * 32 + ((kb ^ (row & 3)) * 8)];
    }
#pragma unroll
    for (int ni = 0; ni < 4; ++ni) {
      const int row = wn * 64 + ni * 16 + r;
      bf[ni] = *(const f16x8*)&Bs[row * 32 + ((kb ^ (row & 3)) * 8)];
    }
#pragma unroll
    for (int mi = 0; mi < 4; ++mi)
#pragma unroll
      for (int ni = 0; ni < 4; ++ni)
        acc[mi][ni] = __builtin_amdgcn_mfma_f32_16x16x32_f16(af[mi], bf[ni], acc[mi][ni], 0, 0, 0);
  }
  const int rb = kb * 4;
#pragma unroll
  for (int mi = 0; mi < 4; ++mi)
#pragma unroll
    for (int ni = 0; ni < 4; ++ni)
#pragma unroll
      for (int j = 0; j < 4; ++j) {
        const int m = m0 + wm * 64 + mi * 16 + rb + j;   // token index (b*512 + t)
        const int n = n0 + wn * 64 + ni * 16 + r;
        const int b = m >> 9, t = m & 511;
        __builtin_nontemporal_store(acc[mi][ni][j], &U[(size_t)(t * BB + b) * RR + n]);
      }
}

// ---------------- the sequential reservoir scan ----------------
// 4 independent batch groups of 16 rows; each group: 64 WGs x 32 cols.
// Per WG: 8 waves k-split (256 k each) -> each state line read ONCE per WG
// (64 KB/CU/step). Partial sums reduced via LDS. Dataflow flags per group.

__launch_bounds__(512, 1)
__global__ void scan_kernel(const float* __restrict__ R, const float* __restrict__ U,
                            f16* __restrict__ S, unsigned* __restrict__ flg) {
  __shared__ __align__(16) char ldsbuf[CPW * RR * 2 + 16 * 1040];  // 128K Rt + 16.25K reduce
  f16* Rt = (f16*)ldsbuf;
  const char* RtB = (const char*)ldsbuf;

  const int wg = blockIdx.x;
  const int grp = wg >> 6, cw = wg & 63;
  const int nbase = cw * CPW;
  const int rbase = grp * RPG;
  const int tid = threadIdx.x;
  const int wv = tid >> 6, l = tid & 63;

  // tau = 1: state_1 = tanh(u_0) on own 16x32 patch; publish early
  const int mm = tid >> 5, cc = tid & 31;   // row-in-group, col-in-slice
  storeS(&S[(size_t)(BB * RR) + (size_t)(rbase + mm) * RR + nbase + cc],
         fast_tanh(U[(size_t)(rbase + mm) * RR + nbase + cc]));
  __syncthreads();
  if (tid == 0) flag_st(&flg[wg], 1u);

  // R column slice -> LDS (chunked conflict-free layout), once
  {
    const int c = tid & 31, kst = tid >> 5;
    for (int k = kst; k < RR; k += 16) {
      const float v = R[(size_t)k * RR + nbase + c];
      const int idx = ((k >> 5) << 10) + ((c >> 4) << 9) +
                      (((c & 15) << 2) + ((k >> 3) & 3)) * 8 + (k & 7);
      Rt[idx] = (f16)v;
    }
  }
  __syncthreads();

  const int r = l & 15, kb = l >> 4;
  // A: row = rbase + r, k = wv*256 + kb*8 + ks*32  (issue8 imm covers ks*64B)
  const unsigned voffA = (unsigned)((((rbase + r) * RR) + wv * 256 + kb * 8) * 2);
  const int bb0 = (r * 4 + kb) * 16;       // byte within 1024B chunk row
  const unsigned* myflags = flg + grp * 64;
  // reduce-read coords for this thread's output element (mm, cc)
  const int ntr = cc >> 4;
  const int lred = (cc & 15) | ((mm >> 2) << 4);
  const int jred = mm & 3;

  f16x8 abuf[8];

  for (int tau = 2; tau <= TT; ++tau) {
    const f16* sprev = S + (size_t)((tau - 1) & 1) * (BB * RR);
    f16* snext = S + (size_t)(tau & 1) * (BB * RR);
    const unsigned need = (unsigned)(tau - 1);

    // u for this thread's output element (independent of flags; hides under poll)
    const float uval = __builtin_nontemporal_load(
        &U[(size_t)(tau - 1) * (BB * RR) + (size_t)(rbase + mm) * RR + nbase + cc]);

    // poll own group's 64 flags
    unsigned fv = flag_ld(&myflags[l]);
    while (!__all(fv >= need)) {
      __builtin_amdgcn_s_sleep(1);
      fv = flag_ld(&myflags[l]);
    }

    // issue all 8 A-loads for this wave's k-range
    issue8(abuf, voffA, sprev);

    f32x4 acc0 = {0.f, 0.f, 0.f, 0.f}, acc1 = {0.f, 0.f, 0.f, 0.f};
#define KSTEP(ks)                                                              \
  {                                                                            \
    const int kc = (wv << 3) + (ks);                                           \
    f16x8 b0 = *(const f16x8*)(RtB + kc * 2048 + bb0);                         \
    f16x8 b1 = *(const f16x8*)(RtB + kc * 2048 + 1024 + bb0);                  \
    acc0 = __builtin_amdgcn_mfma_f32_16x16x32_f16(abuf[ks], b0, acc0, 0, 0, 0);\
    acc1 = __builtin_amdgcn_mfma_f32_16x16x32_f16(abuf[ks], b1, acc1, 0, 0, 0);\
  }
    wait_vm<4>();
    KSTEP(0) KSTEP(1) KSTEP(2) KSTEP(3)
    wait_vm<0>();
    KSTEP(4) KSTEP(5) KSTEP(6) KSTEP(7)
#undef KSTEP

    // partial accumulators -> LDS (padded per-wave copies), then 8-way reduce
    {
      char* red = ldsbuf + CPW * RR * 2;
      *(f32x4*)(red + (wv * 2 + 0) * 1040 + l * 16) = acc0;
      *(f32x4*)(red + (wv * 2 + 1) * 1040 + l * 16) = acc1;
    }
    __syncthreads();
    {
      const char* red = ldsbuf + CPW * RR * 2;
      float s = 0.f;
#pragma unroll
      for (int w = 0; w < 8; ++w)
        s += *(const float*)(red + (w * 2 + ntr) * 1040 + lred * 16 + jred * 4);
      storeS(&snext[(size_t)(rbase + mm) * RR + nbase + cc], fast_tanh(s + uval));
    }
    __syncthreads();                       // all stores drained (vmcnt0 at barrier)
    if (tid == 0) flag_st(&flg[wg], (unsigned)tau);
  }
}

// ---------------- LayerNorm ----------------

__launch_bounds__(256, 1)
__global__ void ln_kernel(const f16* __restrict__ Sfin, const float* __restrict__ gamma,
                          const float* __restrict__ beta, float* __restrict__ out) {
  const int b = blockIdx.x;
  const int tid = threadIdx.x;
  const f16* row = Sfin + (size_t)b * RR;
  float vals[8];
  float lsum = 0.f, lsq = 0.f;
#pragma unroll
  for (int i = 0; i < 8; ++i) {
    float v = (float)row[tid + i * 256];
    vals[i] = v; lsum += v; lsq += v * v;
  }
#pragma unroll
  for (int off = 32; off >= 1; off >>= 1) {
    lsum += __shfl_xor(lsum, off);
    lsq  += __shfl_xor(lsq, off);
  }
  __shared__ float ps[4], pq[4];
  __shared__ float mu_s, rstd_s;
  const int wv = tid >> 6, l = tid & 63;
  if (l == 0) { ps[wv] = lsum; pq[wv] = lsq; }
  __syncthreads();
  if (tid == 0) {
    float s = 0.f, q = 0.f;
    for (int i = 0; i < 4; ++i) { s += ps[i]; q += pq[i]; }
    const float mu = s / RR;
    const float var = q / RR - mu * mu;
    mu_s = mu; rstd_s = rsqrtf(var + 1e-5f);
  }
  __syncthreads();
  const float mu = mu_s, rstd = rstd_s;
#pragma unroll
  for (int i = 0; i < 8; ++i) {
    const int idx = tid + i * 256;
    out[(size_t)b * RR + idx] = (vals[i] - mu) * rstd * gamma[idx] + beta[idx];
  }
}

// ---------------- launch ----------------

extern "C" void kernel_launch(void* const* d_in, const int* in_sizes, int n_in,
                              void* d_out, int out_size, void* d_ws, size_t ws_size,
                              hipStream_t stream) {
  const int*   x     = (const int*)d_in[0];
  const float* ew    = (const float*)d_in[1];
  const float* Rm    = (const float*)d_in[2];
  const float* Win   = (const float*)d_in[3];
  const float* gamma = (const float*)d_in[4];
  const float* beta  = (const float*)d_in[5];

  const size_t U_OFF   = 0;                           // fp32  512*64*2048*4
  const size_t EMB_OFF = 268435456;                   // fp16  32768*512*2
  const size_t WT_OFF  = EMB_OFF + 33554432;          // fp16  2048*512*2
  const size_t S_OFF   = WT_OFF + 2097152;            // fp16  2*64*2048*2
  const size_t BAR_OFF = S_OFF + 524288;              // u32   256 flags
  const size_t NEED    = BAR_OFF + 2048;
  if (ws_size < NEED) {
    hipMemsetAsync(d_out, 0, (size_t)out_size * 4, stream);
    return;
  }
  char* ws = (char*)d_ws;
  float*    Ubuf = (float*)(ws + U_OFF);
  f16*      emb  = (f16*)(ws + EMB_OFF);
  f16*      WinT = (f16*)(ws + WT_OFF);
  f16*      Sbuf = (f16*)(ws + S_OFF);
  unsigned* flg  = (unsigned*)(ws + BAR_OFF);

  hipMemsetAsync(flg, 0, NWGS * sizeof(unsigned), stream);
  prep_emb<<<BB * TT, 128, 0, stream>>>(x, ew, emb);
  prep_winT<<<(EE * RR) / 256, 256, 0, stream>>>(Win, WinT);
  proj_gemm<<<dim3((BB * TT) / 128, RR / 128), 256, 0, stream>>>(emb, WinT, Ubuf);
  scan_kernel<<<NWGS, 512, 0, stream>>>(Rm, Ubuf, Sbuf, flg);
  // state_512 lives at instance 512&1 == 0
  ln_kernel<<<BB, 256, 0, stream>>>(Sbuf, gamma, beta, (float*)d_out);
}

// Round 5
// 3328.197 us; speedup vs baseline: 4.6647x; 1.2256x over previous
//
#include <hip/hip_runtime.h>

#define BB 64
#define TT 512
#define EE 512
#define RR 2048
#define CPW 32    // columns per scan workgroup
#define RPG 16    // rows (batch) per group
#define NWGS 256  // 4 groups x 64 col-WGs

typedef _Float16 f16;
typedef f16 f16x8 __attribute__((ext_vector_type(8)));
typedef float f32x4 __attribute__((ext_vector_type(4)));

__device__ __forceinline__ void gload16(const void* g, void* l) {
  __builtin_amdgcn_global_load_lds(
      (const __attribute__((address_space(1))) void*)g,
      (__attribute__((address_space(3))) void*)l, 16, 0, 0);
}

__device__ __forceinline__ float fast_tanh(float v) {
  float e = __expf(2.0f * v);
  return 1.0f - 2.0f / (e + 1.0f);
}

// write-through device-coherent 2B store (R2-R4 proven)
__device__ __forceinline__ void storeS(f16* p, float v) {
  union { f16 h; unsigned short s; } u;
  u.h = (f16)v;
  __hip_atomic_store((unsigned short*)p, u.s, __ATOMIC_RELAXED, __HIP_MEMORY_SCOPE_AGENT);
}

__device__ __forceinline__ unsigned flag_ld(const unsigned* p) {
  return __hip_atomic_load(p, __ATOMIC_RELAXED, __HIP_MEMORY_SCOPE_AGENT);
}
__device__ __forceinline__ void flag_st(unsigned* p, unsigned v) {
  __hip_atomic_store(p, v, __ATOMIC_RELAXED, __HIP_MEMORY_SCOPE_AGENT);
}

// batch of 8 ORDINARY CACHED 16B loads (L1/L2-cacheable; coherence via the
// per-step acquire fence), imm offsets 0..448
__device__ __forceinline__ void issue8(f16x8* dst, unsigned voff, const f16* sbase) {
#pragma unroll
  for (int i = 0; i < 8; ++i)
    asm volatile("global_load_dwordx4 %0, %1, %2 offset:%c3"
                 : "=v"(dst[i]) : "v"(voff), "s"(sbase), "i"(64 * i) : "memory");
}

template <int N>
__device__ __forceinline__ void wait_vm() {
  asm volatile("s_waitcnt vmcnt(%c0)" :: "i"(N) : "memory");
  __builtin_amdgcn_sched_barrier(0);   // rule #18
}

// ---------------- prep kernels ----------------

__global__ void prep_emb(const int* __restrict__ x, const float* __restrict__ ew,
                         f16* __restrict__ emb) {
  const int row = blockIdx.x;            // token index (b*T + t)
  const int tok = x[row];
  const float4* src = (const float4*)(ew + (size_t)tok * EE);
  f16* dst = emb + (size_t)row * EE;
  const int i = threadIdx.x;             // 128 threads, 4 f16 each
  float4 v = src[i];
  union { f16 h[4]; unsigned long long u; } p;
  p.h[0] = (f16)v.x; p.h[1] = (f16)v.y; p.h[2] = (f16)v.z; p.h[3] = (f16)v.w;
  ((unsigned long long*)dst)[i] = p.u;
}

__global__ void prep_winT(const float* __restrict__ Win, f16* __restrict__ WinT) {
  const int i = blockIdx.x * blockDim.x + threadIdx.x;  // over EE*RR
  if (i < EE * RR) {
    const int k = i / RR, n = i % RR;
    WinT[(size_t)n * EE + k] = (f16)Win[i];
  }
}

// ---------------- projection GEMM: U[t][b][n] = emb[b,t,:] @ Win[:,n] ----------------

__launch_bounds__(256, 1)
__global__ void proj_gemm(const f16* __restrict__ A, const f16* __restrict__ Bt,
                          float* __restrict__ U) {
  __shared__ f16 As[128 * 32];
  __shared__ f16 Bs[128 * 32];
  const int tid = threadIdx.x;
  const int wv = tid >> 6, l = tid & 63;
  const int m0 = blockIdx.x * 128, n0 = blockIdx.y * 128;
  const int wm = wv >> 1, wn = wv & 1;
  const int srow = tid >> 2, sc = tid & 3;
  const int r = l & 15, kb = l >> 4;
  f32x4 acc[4][4] = {};

  for (int k0 = 0; k0 < EE; k0 += 32) {
    __syncthreads();
#pragma unroll
    for (int q = 0; q < 2; ++q) {
      const int row = q * 64 + srow;
      const int cc = sc ^ (row & 3);
      gload16(A + (size_t)(m0 + row) * EE + k0 + cc * 8,
              (char*)As + q * 4096 + wv * 1024);
      gload16(Bt + (size_t)(n0 + row) * EE + k0 + cc * 8,
              (char*)Bs + q * 4096 + wv * 1024);
    }
    __syncthreads();
    f16x8 af[4], bf[4];
#pragma unroll
    for (int mi = 0; mi < 4; ++mi) {
      const int row = wm * 64 + mi * 16 + r;
      af[mi] = *(const f16x8*)&As[row * 32 + ((kb ^ (row & 3)) * 8)];
    }
#pragma unroll
    for (int ni = 0; ni < 4; ++ni) {
      const int row = wn * 64 + ni * 16 + r;
      bf[ni] = *(const f16x8*)&Bs[row * 32 + ((kb ^ (row & 3)) * 8)];
    }
#pragma unroll
    for (int mi = 0; mi < 4; ++mi)
#pragma unroll
      for (int ni = 0; ni < 4; ++ni)
        acc[mi][ni] = __builtin_amdgcn_mfma_f32_16x16x32_f16(af[mi], bf[ni], acc[mi][ni], 0, 0, 0);
  }
  const int rb = kb * 4;
#pragma unroll
  for (int mi = 0; mi < 4; ++mi)
#pragma unroll
    for (int ni = 0; ni < 4; ++ni)
#pragma unroll
      for (int j = 0; j < 4; ++j) {
        const int m = m0 + wm * 64 + mi * 16 + rb + j;   // token index (b*512 + t)
        const int n = n0 + wn * 64 + ni * 16 + r;
        const int b = m >> 9, t = m & 511;
        __builtin_nontemporal_store(acc[mi][ni][j], &U[(size_t)(t * BB + b) * RR + n]);
      }
}

// ---------------- the sequential reservoir scan ----------------
// 4 batch-groups x 64 col-WGs. Group g pinned to XCD pair {2g,2g+1} via
// grp=(wg&7)>>1 (blockIdx%8 == XCD heuristic): a group's cache invalidates
// only touch its own XCDs, whose WGs are phase-aligned by the shared flags.
// State reads are CACHED; one acquire-fence (L1+L2 inv) per WG per step,
// right after the poll, makes them coherent. State writes stay write-through.

__launch_bounds__(512, 1)
__global__ void scan_kernel(const float* __restrict__ R, const float* __restrict__ U,
                            f16* __restrict__ S, unsigned* __restrict__ flg) {
  __shared__ __align__(16) char ldsbuf[CPW * RR * 2 + 16 * 1040];  // 128K Rt + reduce buf
  f16* Rt = (f16*)ldsbuf;
  const char* RtB = (const char*)ldsbuf;

  const int wg = blockIdx.x;
  const int grp = (wg & 7) >> 1;                 // XCD-pair pinned group
  const int cw = ((wg >> 3) << 1) | (wg & 1);    // 0..63 within group
  const int nbase = cw * CPW;
  const int rbase = grp * RPG;
  const int tid = threadIdx.x;
  const int wv = tid >> 6, l = tid & 63;
  unsigned* myflags = flg + grp * 64;

  // tau = 1: state_1 = tanh(u_0) on own 16x32 patch; publish early
  const int mm = tid >> 5, cc = tid & 31;   // row-in-group, col-in-slice
  storeS(&S[(size_t)(BB * RR) + (size_t)(rbase + mm) * RR + nbase + cc],
         fast_tanh(U[(size_t)(rbase + mm) * RR + nbase + cc]));
  __syncthreads();
  if (tid == 0) flag_st(&myflags[cw], 1u);

  // R column slice -> LDS (chunked conflict-free layout), once
  {
    const int c = tid & 31, kst = tid >> 5;
    for (int k = kst; k < RR; k += 16) {
      const float v = R[(size_t)k * RR + nbase + c];
      const int idx = ((k >> 5) << 10) + ((c >> 4) << 9) +
                      (((c & 15) << 2) + ((k >> 3) & 3)) * 8 + (k & 7);
      Rt[idx] = (f16)v;
    }
  }
  __syncthreads();

  const int r = l & 15, kb = l >> 4;
  const int kblk = (wv + cw) & 7;          // k-rotation: de-hotspot the L3 fetch
  // A: row = rbase + r, k = kblk*256 + kb*8 + ks*32 (issue8 imm covers ks*64B)
  const unsigned voffA = (unsigned)((((rbase + r) * RR) + (kblk << 8) + kb * 8) * 2);
  const int bb0 = (r * 4 + kb) * 16;       // byte within 1024B chunk row
  // reduce-read coords for this thread's output element (mm, cc)
  const int ntr = cc >> 4;
  const int lred = (cc & 15) | ((mm >> 2) << 4);
  const int jred = mm & 3;

  f16x8 abuf[8];

  for (int tau = 2; tau <= TT; ++tau) {
    const f16* sprev = S + (size_t)((tau - 1) & 1) * (BB * RR);
    f16* snext = S + (size_t)(tau & 1) * (BB * RR);
    const unsigned need = (unsigned)(tau - 1);

    // u for this thread's output element (pre-poll; value lands in a register)
    const float uval = __builtin_nontemporal_load(
        &U[(size_t)(tau - 1) * (BB * RR) + (size_t)(rbase + mm) * RR + nbase + cc]);

    // wave 0 polls own group's 64 flags; others park at the barrier
    if (wv == 0) {
      unsigned fv = flag_ld(&myflags[l]);
      while (!__all(fv >= need)) {
        __builtin_amdgcn_s_sleep(1);
        fv = flag_ld(&myflags[l]);
      }
    }
    __syncthreads();
    // one L1+L2 invalidate per WG per step; all group members are here
    // simultaneously, so the invs cluster BEFORE the fetch burst
    if (wv == 0) __builtin_amdgcn_fence(__ATOMIC_ACQUIRE, "agent");
    __syncthreads();

    // issue all 8 cached A-loads for this wave's (rotated) k-range
    issue8(abuf, voffA, sprev);

    f32x4 acc0 = {0.f, 0.f, 0.f, 0.f}, acc1 = {0.f, 0.f, 0.f, 0.f};
#define KSTEP(ks)                                                              \
  {                                                                            \
    const int kc = (kblk << 3) + (ks);                                         \
    f16x8 b0 = *(const f16x8*)(RtB + kc * 2048 + bb0);                         \
    f16x8 b1 = *(const f16x8*)(RtB + kc * 2048 + 1024 + bb0);                  \
    acc0 = __builtin_amdgcn_mfma_f32_16x16x32_f16(abuf[ks], b0, acc0, 0, 0, 0);\
    acc1 = __builtin_amdgcn_mfma_f32_16x16x32_f16(abuf[ks], b1, acc1, 0, 0, 0);\
  }
    wait_vm<4>();
    KSTEP(0) KSTEP(1) KSTEP(2) KSTEP(3)
    wait_vm<0>();
    KSTEP(4) KSTEP(5) KSTEP(6) KSTEP(7)
#undef KSTEP

    // partial accumulators -> LDS (padded per-wave copies), then 8-way reduce
    {
      char* red = ldsbuf + CPW * RR * 2;
      *(f32x4*)(red + (wv * 2 + 0) * 1040 + l * 16) = acc0;
      *(f32x4*)(red + (wv * 2 + 1) * 1040 + l * 16) = acc1;
    }
    __syncthreads();
    {
      const char* red = ldsbuf + CPW * RR * 2;
      float s = 0.f;
#pragma unroll
      for (int w = 0; w < 8; ++w)
        s += *(const float*)(red + (w * 2 + ntr) * 1040 + lred * 16 + jred * 4);
      storeS(&snext[(size_t)(rbase + mm) * RR + nbase + cc], fast_tanh(s + uval));
    }
    __syncthreads();                       // all waves' stores drained
    if (tid == 0) flag_st(&myflags[cw], (unsigned)tau);
  }
}

// ---------------- LayerNorm ----------------

__launch_bounds__(256, 1)
__global__ void ln_kernel(const f16* __restrict__ Sfin, const float* __restrict__ gamma,
                          const float* __restrict__ beta, float* __restrict__ out) {
  const int b = blockIdx.x;
  const int tid = threadIdx.x;
  const f16* row = Sfin + (size_t)b * RR;
  float vals[8];
  float lsum = 0.f, lsq = 0.f;
#pragma unroll
  for (int i = 0; i < 8; ++i) {
    float v = (float)row[tid + i * 256];
    vals[i] = v; lsum += v; lsq += v * v;
  }
#pragma unroll
  for (int off = 32; off >= 1; off >>= 1) {
    lsum += __shfl_xor(lsum, off);
    lsq  += __shfl_xor(lsq, off);
  }
  __shared__ float ps[4], pq[4];
  __shared__ float mu_s, rstd_s;
  const int wv = tid >> 6, l = tid & 63;
  if (l == 0) { ps[wv] = lsum; pq[wv] = lsq; }
  __syncthreads();
  if (tid == 0) {
    float s = 0.f, q = 0.f;
    for (int i = 0; i < 4; ++i) { s += ps[i]; q += pq[i]; }
    const float mu = s / RR;
    const float var = q / RR - mu * mu;
    mu_s = mu; rstd_s = rsqrtf(var + 1e-5f);
  }
  __syncthreads();
  const float mu = mu_s, rstd = rstd_s;
#pragma unroll
  for (int i = 0; i < 8; ++i) {
    const int idx = tid + i * 256;
    out[(size_t)b * RR + idx] = (vals[i] - mu) * rstd * gamma[idx] + beta[idx];
  }
}

// ---------------- launch ----------------

extern "C" void kernel_launch(void* const* d_in, const int* in_sizes, int n_in,
                              void* d_out, int out_size, void* d_ws, size_t ws_size,
                              hipStream_t stream) {
  const int*   x     = (const int*)d_in[0];
  const float* ew    = (const float*)d_in[1];
  const float* Rm    = (const float*)d_in[2];
  const float* Win   = (const float*)d_in[3];
  const float* gamma = (const float*)d_in[4];
  const float* beta  = (const float*)d_in[5];

  const size_t U_OFF   = 0;                           // fp32  512*64*2048*4
  const size_t EMB_OFF = 268435456;                   // fp16  32768*512*2
  const size_t WT_OFF  = EMB_OFF + 33554432;          // fp16  2048*512*2
  const size_t S_OFF   = WT_OFF + 2097152;            // fp16  2*64*2048*2
  const size_t BAR_OFF = S_OFF + 524288;              // u32   256 flags
  const size_t NEED    = BAR_OFF + 2048;
  if (ws_size < NEED) {
    hipMemsetAsync(d_out, 0, (size_t)out_size * 4, stream);
    return;
  }
  char* ws = (char*)d_ws;
  float*    Ubuf = (float*)(ws + U_OFF);
  f16*      emb  = (f16*)(ws + EMB_OFF);
  f16*      WinT = (f16*)(ws + WT_OFF);
  f16*      Sbuf = (f16*)(ws + S_OFF);
  unsigned* flg  = (unsigned*)(ws + BAR_OFF);

  hipMemsetAsync(flg, 0, NWGS * sizeof(unsigned), stream);
  prep_emb<<<BB * TT, 128, 0, stream>>>(x, ew, emb);
  prep_winT<<<(EE * RR) / 256, 256, 0, stream>>>(Win, WinT);
  proj_gemm<<<dim3((BB * TT) / 128, RR / 128), 256, 0, stream>>>(emb, WinT, Ubuf);
  scan_kernel<<<NWGS, 512, 0, stream>>>(Rm, Ubuf, Sbuf, flg);
  // state_512 lives at instance 512&1 == 0
  ln_kernel<<<BB, 256, 0, stream>>>(Sbuf, gamma, beta, (float*)d_out);
}

// Round 6
// 2043.694 us; speedup vs baseline: 7.5965x; 1.6285x over previous
//
#include <hip/hip_runtime.h>

#define BB 64
#define TT 512
#define EE 512
#define RR 2048
#define CPW 32    // columns per scan workgroup
#define RPG 16    // rows (batch) per group
#define NWGS 256  // 4 groups x 64 col-WGs

typedef _Float16 f16;
typedef f16 f16x8 __attribute__((ext_vector_type(8)));
typedef float f32x4 __attribute__((ext_vector_type(4)));

__device__ __forceinline__ void gload16(const void* g, void* l) {
  __builtin_amdgcn_global_load_lds(
      (const __attribute__((address_space(1))) void*)g,
      (__attribute__((address_space(3))) void*)l, 16, 0, 0);
}

__device__ __forceinline__ float fast_tanh(float v) {
  float e = __expf(2.0f * v);
  return 1.0f - 2.0f / (e + 1.0f);
}

// write-through device-coherent 2B store (R2-R5 proven)
__device__ __forceinline__ void storeS(f16* p, float v) {
  union { f16 h; unsigned short s; } u;
  u.h = (f16)v;
  __hip_atomic_store((unsigned short*)p, u.s, __ATOMIC_RELAXED, __HIP_MEMORY_SCOPE_AGENT);
}

__device__ __forceinline__ unsigned flag_ld(const unsigned* p) {
  return __hip_atomic_load(p, __ATOMIC_RELAXED, __HIP_MEMORY_SCOPE_AGENT);
}
__device__ __forceinline__ void flag_st(unsigned* p, unsigned v) {
  __hip_atomic_store(p, v, __ATOMIC_RELAXED, __HIP_MEMORY_SCOPE_AGENT);
}

// batch of 8 L1-BYPASS (sc0) 16B loads served from L2; L2 freshness comes
// from the per-XCD leader invalidate + L3 write-through stores
__device__ __forceinline__ void issue8(f16x8* dst, unsigned voff, const f16* sbase) {
#pragma unroll
  for (int i = 0; i < 8; ++i)
    asm volatile("global_load_dwordx4 %0, %1, %2 offset:%c3 sc0"
                 : "=v"(dst[i]) : "v"(voff), "s"(sbase), "i"(64 * i) : "memory");
}

template <int N>
__device__ __forceinline__ void wait_vm() {
  asm volatile("s_waitcnt vmcnt(%c0)" :: "i"(N) : "memory");
  __builtin_amdgcn_sched_barrier(0);   // rule #18
}

// ---------------- prep kernels ----------------

__global__ void prep_emb(const int* __restrict__ x, const float* __restrict__ ew,
                         f16* __restrict__ emb) {
  const int row = blockIdx.x;            // token index (b*T + t)
  const int tok = x[row];
  const float4* src = (const float4*)(ew + (size_t)tok * EE);
  f16* dst = emb + (size_t)row * EE;
  const int i = threadIdx.x;             // 128 threads, 4 f16 each
  float4 v = src[i];
  union { f16 h[4]; unsigned long long u; } p;
  p.h[0] = (f16)v.x; p.h[1] = (f16)v.y; p.h[2] = (f16)v.z; p.h[3] = (f16)v.w;
  ((unsigned long long*)dst)[i] = p.u;
}

__global__ void prep_winT(const float* __restrict__ Win, f16* __restrict__ WinT) {
  const int i = blockIdx.x * blockDim.x + threadIdx.x;  // over EE*RR
  if (i < EE * RR) {
    const int k = i / RR, n = i % RR;
    WinT[(size_t)n * EE + k] = (f16)Win[i];
  }
}

// ---------------- projection GEMM: U[t][b][n] = emb[b,t,:] @ Win[:,n] ----------------

__launch_bounds__(256, 1)
__global__ void proj_gemm(const f16* __restrict__ A, const f16* __restrict__ Bt,
                          float* __restrict__ U) {
  __shared__ f16 As[128 * 32];
  __shared__ f16 Bs[128 * 32];
  const int tid = threadIdx.x;
  const int wv = tid >> 6, l = tid & 63;
  const int m0 = blockIdx.x * 128, n0 = blockIdx.y * 128;
  const int wm = wv >> 1, wn = wv & 1;
  const int srow = tid >> 2, sc = tid & 3;
  const int r = l & 15, kb = l >> 4;
  f32x4 acc[4][4] = {};

  for (int k0 = 0; k0 < EE; k0 += 32) {
    __syncthreads();
#pragma unroll
    for (int q = 0; q < 2; ++q) {
      const int row = q * 64 + srow;
      const int cc = sc ^ (row & 3);
      gload16(A + (size_t)(m0 + row) * EE + k0 + cc * 8,
              (char*)As + q * 4096 + wv * 1024);
      gload16(Bt + (size_t)(n0 + row) * EE + k0 + cc * 8,
              (char*)Bs + q * 4096 + wv * 1024);
    }
    __syncthreads();
    f16x8 af[4], bf[4];
#pragma unroll
    for (int mi = 0; mi < 4; ++mi) {
      const int row = wm * 64 + mi * 16 + r;
      af[mi] = *(const f16x8*)&As[row * 32 + ((kb ^ (row & 3)) * 8)];
    }
#pragma unroll
    for (int ni = 0; ni < 4; ++ni) {
      const int row = wn * 64 + ni * 16 + r;
      bf[ni] = *(const f16x8*)&Bs[row * 32 + ((kb ^ (row & 3)) * 8)];
    }
#pragma unroll
    for (int mi = 0; mi < 4; ++mi)
#pragma unroll
      for (int ni = 0; ni < 4; ++ni)
        acc[mi][ni] = __builtin_amdgcn_mfma_f32_16x16x32_f16(af[mi], bf[ni], acc[mi][ni], 0, 0, 0);
  }
  const int rb = kb * 4;
#pragma unroll
  for (int mi = 0; mi < 4; ++mi)
#pragma unroll
    for (int ni = 0; ni < 4; ++ni)
#pragma unroll
      for (int j = 0; j < 4; ++j) {
        const int m = m0 + wm * 64 + mi * 16 + rb + j;   // token index (b*512 + t)
        const int n = n0 + wn * 64 + ni * 16 + r;
        const int b = m >> 9, t = m & 511;
        __builtin_nontemporal_store(acc[mi][ni][j], &U[(size_t)(t * BB + b) * RR + n]);
      }
}

// ---------------- the sequential reservoir scan ----------------
// 4 batch-groups x 64 col-WGs, group pinned to XCD pair {2g,2g+1}.
// Coherence: state writes are write-through (reach L3 = coherence point);
// state reads are sc0 loads (bypass stale L1, served by L2); one leader WG
// per XCD invalidates L2 (agent acquire) at its own step-top, OFF the
// critical path, and publishes fflag[xcd]=tau. Every load is guarded by
// its producer-octet's flags, so post-fence misses always see fresh L3.

__launch_bounds__(512, 1)
__global__ void scan_kernel(const float* __restrict__ R, const float* __restrict__ U,
                            f16* __restrict__ S, unsigned* __restrict__ flg,
                            unsigned* __restrict__ fflag) {
  __shared__ __align__(16) char ldsbuf[CPW * RR * 2 + 16 * 1040];  // 128K Rt + reduce buf
  f16* Rt = (f16*)ldsbuf;
  const char* RtB = (const char*)ldsbuf;

  const int wg = blockIdx.x;
  const int xcd = wg & 7;                        // blockIdx%8 == XCD heuristic
  const int grp = xcd >> 1;                      // group on XCD pair
  const int cw = ((wg >> 3) << 1) | (wg & 1);    // 0..63 within group
  const bool leader = (wg >> 3) == 0;            // one leader WG per XCD
  const int nbase = cw * CPW;
  const int rbase = grp * RPG;
  const int tid = threadIdx.x;
  const int wv = tid >> 6, l = tid & 63;
  unsigned* myflags = flg + grp * 64;
  unsigned* myff = fflag + xcd * 32;             // 128B-padded per-XCD flag

  // tau = 1: state_1 = tanh(u_0) on own 16x32 patch; publish early
  const int mm = tid >> 5, cc = tid & 31;   // row-in-group, col-in-slice
  storeS(&S[(size_t)(BB * RR) + (size_t)(rbase + mm) * RR + nbase + cc],
         fast_tanh(U[(size_t)(rbase + mm) * RR + nbase + cc]));
  __syncthreads();
  if (tid == 0) flag_st(&myflags[cw], 1u);

  // R column slice -> LDS (chunked conflict-free layout), once
  {
    const int c = tid & 31, kst = tid >> 5;
    for (int k = kst; k < RR; k += 16) {
      const float v = R[(size_t)k * RR + nbase + c];
      const int idx = ((k >> 5) << 10) + ((c >> 4) << 9) +
                      (((c & 15) << 2) + ((k >> 3) & 3)) * 8 + (k & 7);
      Rt[idx] = (f16)v;
    }
  }
  __syncthreads();

  const int r = l & 15, kb = l >> 4;
  const int kblk = (wv + cw) & 7;          // k-rotation: stagger producer demand
  // A: row = rbase + r, k = kblk*256 + kb*8 + ks*32 (issue8 imm covers ks*64B)
  const unsigned voffA = (unsigned)((((rbase + r) * RR) + (kblk << 8) + kb * 8) * 2);
  const int bb0 = (r * 4 + kb) * 16;       // byte within 1024B chunk row
  // reduce-read coords for this thread's output element (mm, cc)
  const int ntr = cc >> 4;
  const int lred = (cc & 15) | ((mm >> 2) << 4);
  const int jred = mm & 3;

  f16x8 abuf[8];

  for (int tau = 2; tau <= TT; ++tau) {
    const f16* sprev = S + (size_t)((tau - 1) & 1) * (BB * RR);
    f16* snext = S + (size_t)(tau & 1) * (BB * RR);
    const unsigned need = (unsigned)(tau - 1);

    // u for this thread's output element (pre-poll; lands in a register)
    const float uval = __builtin_nontemporal_load(
        &U[(size_t)(tau - 1) * (BB * RR) + (size_t)(rbase + mm) * RR + nbase + cc]);

    // per-XCD leader: invalidate L2 NOW (off critical path) and publish.
    // followers: confirm this XCD's invalidate for step tau happened.
    if (wv == 0) {
      if (leader) {
        __builtin_amdgcn_fence(__ATOMIC_ACQUIRE, "agent");
        if (l == 0) flag_st(myff, (unsigned)tau);
      } else if (l == 0) {
        unsigned fv = flag_ld(myff);
        while (fv < (unsigned)tau) {
          __builtin_amdgcn_s_sleep(1);
          fv = flag_ld(myff);
        }
      }
    }
    __syncthreads();

    // per-wave poll: only this wave's 8 producers (one 32B flag line)
    {
      unsigned fv = flag_ld(&myflags[kblk * 8 + (l & 7)]);
      while (!__all(fv >= need)) {
        __builtin_amdgcn_s_sleep(1);
        fv = flag_ld(&myflags[kblk * 8 + (l & 7)]);
      }
    }

    // issue all 8 sc0 A-loads for this wave's (rotated) k-range
    issue8(abuf, voffA, sprev);

    f32x4 acc0 = {0.f, 0.f, 0.f, 0.f}, acc1 = {0.f, 0.f, 0.f, 0.f};
#define KSTEP(ks)                                                              \
  {                                                                            \
    const int kc = (kblk << 3) + (ks);                                         \
    f16x8 b0 = *(const f16x8*)(RtB + kc * 2048 + bb0);                         \
    f16x8 b1 = *(const f16x8*)(RtB + kc * 2048 + 1024 + bb0);                  \
    acc0 = __builtin_amdgcn_mfma_f32_16x16x32_f16(abuf[ks], b0, acc0, 0, 0, 0);\
    acc1 = __builtin_amdgcn_mfma_f32_16x16x32_f16(abuf[ks], b1, acc1, 0, 0, 0);\
  }
    wait_vm<4>();
    KSTEP(0) KSTEP(1) KSTEP(2) KSTEP(3)
    wait_vm<0>();
    KSTEP(4) KSTEP(5) KSTEP(6) KSTEP(7)
#undef KSTEP

    // partial accumulators -> LDS (padded per-wave copies), then 8-way reduce
    {
      char* red = ldsbuf + CPW * RR * 2;
      *(f32x4*)(red + (wv * 2 + 0) * 1040 + l * 16) = acc0;
      *(f32x4*)(red + (wv * 2 + 1) * 1040 + l * 16) = acc1;
    }
    __syncthreads();
    {
      const char* red = ldsbuf + CPW * RR * 2;
      float s = 0.f;
#pragma unroll
      for (int w = 0; w < 8; ++w)
        s += *(const float*)(red + (w * 2 + ntr) * 1040 + lred * 16 + jred * 4);
      storeS(&snext[(size_t)(rbase + mm) * RR + nbase + cc], fast_tanh(s + uval));
    }
    __syncthreads();                       // all waves' stores drained
    if (tid == 0) flag_st(&myflags[cw], (unsigned)tau);
  }
}

// ---------------- LayerNorm ----------------

__launch_bounds__(256, 1)
__global__ void ln_kernel(const f16* __restrict__ Sfin, const float* __restrict__ gamma,
                          const float* __restrict__ beta, float* __restrict__ out) {
  const int b = blockIdx.x;
  const int tid = threadIdx.x;
  const f16* row = Sfin + (size_t)b * RR;
  float vals[8];
  float lsum = 0.f, lsq = 0.f;
#pragma unroll
  for (int i = 0; i < 8; ++i) {
    float v = (float)row[tid + i * 256];
    vals[i] = v; lsum += v; lsq += v * v;
  }
#pragma unroll
  for (int off = 32; off >= 1; off >>= 1) {
    lsum += __shfl_xor(lsum, off);
    lsq  += __shfl_xor(lsq, off);
  }
  __shared__ float ps[4], pq[4];
  __shared__ float mu_s, rstd_s;
  const int wv = tid >> 6, l = tid & 63;
  if (l == 0) { ps[wv] = lsum; pq[wv] = lsq; }
  __syncthreads();
  if (tid == 0) {
    float s = 0.f, q = 0.f;
    for (int i = 0; i < 4; ++i) { s += ps[i]; q += pq[i]; }
    const float mu = s / RR;
    const float var = q / RR - mu * mu;
    mu_s = mu; rstd_s = rsqrtf(var + 1e-5f);
  }
  __syncthreads();
  const float mu = mu_s, rstd = rstd_s;
#pragma unroll
  for (int i = 0; i < 8; ++i) {
    const int idx = tid + i * 256;
    out[(size_t)b * RR + idx] = (vals[i] - mu) * rstd * gamma[idx] + beta[idx];
  }
}

// ---------------- launch ----------------

extern "C" void kernel_launch(void* const* d_in, const int* in_sizes, int n_in,
                              void* d_out, int out_size, void* d_ws, size_t ws_size,
                              hipStream_t stream) {
  const int*   x     = (const int*)d_in[0];
  const float* ew    = (const float*)d_in[1];
  const float* Rm    = (const float*)d_in[2];
  const float* Win   = (const float*)d_in[3];
  const float* gamma = (const float*)d_in[4];
  const float* beta  = (const float*)d_in[5];

  const size_t U_OFF   = 0;                           // fp32  512*64*2048*4
  const size_t EMB_OFF = 268435456;                   // fp16  32768*512*2
  const size_t WT_OFF  = EMB_OFF + 33554432;          // fp16  2048*512*2
  const size_t S_OFF   = WT_OFF + 2097152;            // fp16  2*64*2048*2
  const size_t BAR_OFF = S_OFF + 524288;              // u32   256 group flags
  const size_t FF_OFF  = BAR_OFF + 1024;              // u32   8 x 32 (128B-padded)
  const size_t NEED    = FF_OFF + 1024;
  if (ws_size < NEED) {
    hipMemsetAsync(d_out, 0, (size_t)out_size * 4, stream);
    return;
  }
  char* ws = (char*)d_ws;
  float*    Ubuf  = (float*)(ws + U_OFF);
  f16*      emb   = (f16*)(ws + EMB_OFF);
  f16*      WinT  = (f16*)(ws + WT_OFF);
  f16*      Sbuf  = (f16*)(ws + S_OFF);
  unsigned* flg   = (unsigned*)(ws + BAR_OFF);
  unsigned* fflag = (unsigned*)(ws + FF_OFF);

  hipMemsetAsync(flg, 0, 2048, stream);   // group flags + fence flags
  prep_emb<<<BB * TT, 128, 0, stream>>>(x, ew, emb);
  prep_winT<<<(EE * RR) / 256, 256, 0, stream>>>(Win, WinT);
  proj_gemm<<<dim3((BB * TT) / 128, RR / 128), 256, 0, stream>>>(emb, WinT, Ubuf);
  scan_kernel<<<NWGS, 512, 0, stream>>>(Rm, Ubuf, Sbuf, flg, fflag);
  // state_512 lives at instance 512&1 == 0
  ln_kernel<<<BB, 256, 0, stream>>>(Sbuf, gamma, beta, (float*)d_out);
}

// Round 7
// 1999.178 us; speedup vs baseline: 7.7656x; 1.0223x over previous
//
#include <hip/hip_runtime.h>

#define BB 64
#define TT 512
#define EE 512
#define RR 2048
#define CPW 32    // columns per scan workgroup
#define RPG 16    // rows (batch) per group
#define NWGS 256  // 4 groups x 64 col-WGs
#define FPAD 16   // flag padding: 16 u32 = 64 B/flag

typedef _Float16 f16;
typedef f16 f16x8 __attribute__((ext_vector_type(8)));
typedef float f32x4 __attribute__((ext_vector_type(4)));

__device__ __forceinline__ void gload16(const void* g, void* l) {
  __builtin_amdgcn_global_load_lds(
      (const __attribute__((address_space(1))) void*)g,
      (__attribute__((address_space(3))) void*)l, 16, 0, 0);
}

__device__ __forceinline__ float fast_tanh(float v) {
  float e = __expf(2.0f * v);
  return 1.0f - 2.0f / (e + 1.0f);
}

// write-through device-coherent 2B store (R2-R6 proven)
__device__ __forceinline__ void storeS(f16* p, float v) {
  union { f16 h; unsigned short s; } u;
  u.h = (f16)v;
  __hip_atomic_store((unsigned short*)p, u.s, __ATOMIC_RELAXED, __HIP_MEMORY_SCOPE_AGENT);
}

__device__ __forceinline__ unsigned flag_ld(const unsigned* p) {
  return __hip_atomic_load(p, __ATOMIC_RELAXED, __HIP_MEMORY_SCOPE_AGENT);
}
__device__ __forceinline__ void flag_st(unsigned* p, unsigned v) {
  __hip_atomic_store(p, v, __ATOMIC_RELAXED, __HIP_MEMORY_SCOPE_AGENT);
}

// batch of 8 L1-BYPASS (sc0) 16B loads served from L2 (freshness: per-XCD
// service-wave invalidate + L3 write-through stores)
__device__ __forceinline__ void issue8(f16x8* dst, unsigned voff, const f16* sbase) {
#pragma unroll
  for (int i = 0; i < 8; ++i)
    asm volatile("global_load_dwordx4 %0, %1, %2 offset:%c3 sc0"
                 : "=v"(dst[i]) : "v"(voff), "s"(sbase), "i"(64 * i) : "memory");
}

__device__ __forceinline__ unsigned bypass_ld(unsigned voff, const unsigned* base) {
  unsigned v;
  asm volatile("global_load_dword %0, %1, %2 sc0 sc1"
               : "=v"(v) : "v"(voff), "s"(base) : "memory");
  return v;
}

template <int N>
__device__ __forceinline__ void wait_vm() {
  asm volatile("s_waitcnt vmcnt(%c0)" :: "i"(N) : "memory");
  __builtin_amdgcn_sched_barrier(0);   // rule #18
}

// ---------------- prep kernels ----------------

__global__ void prep_emb(const int* __restrict__ x, const float* __restrict__ ew,
                         f16* __restrict__ emb) {
  const int row = blockIdx.x;            // token index (b*T + t)
  const int tok = x[row];
  const float4* src = (const float4*)(ew + (size_t)tok * EE);
  f16* dst = emb + (size_t)row * EE;
  const int i = threadIdx.x;             // 128 threads, 4 f16 each
  float4 v = src[i];
  union { f16 h[4]; unsigned long long u; } p;
  p.h[0] = (f16)v.x; p.h[1] = (f16)v.y; p.h[2] = (f16)v.z; p.h[3] = (f16)v.w;
  ((unsigned long long*)dst)[i] = p.u;
}

__global__ void prep_winT(const float* __restrict__ Win, f16* __restrict__ WinT) {
  const int i = blockIdx.x * blockDim.x + threadIdx.x;  // over EE*RR
  if (i < EE * RR) {
    const int k = i / RR, n = i % RR;
    WinT[(size_t)n * EE + k] = (f16)Win[i];
  }
}

// ---------------- projection GEMM: U[t][b][n] = emb[b,t,:] @ Win[:,n] ----------------

__launch_bounds__(256, 1)
__global__ void proj_gemm(const f16* __restrict__ A, const f16* __restrict__ Bt,
                          float* __restrict__ U) {
  __shared__ f16 As[128 * 32];
  __shared__ f16 Bs[128 * 32];
  const int tid = threadIdx.x;
  const int wv = tid >> 6, l = tid & 63;
  const int m0 = blockIdx.x * 128, n0 = blockIdx.y * 128;
  const int wm = wv >> 1, wn = wv & 1;
  const int srow = tid >> 2, sc = tid & 3;
  const int r = l & 15, kb = l >> 4;
  f32x4 acc[4][4] = {};

  for (int k0 = 0; k0 < EE; k0 += 32) {
    __syncthreads();
#pragma unroll
    for (int q = 0; q < 2; ++q) {
      const int row = q * 64 + srow;
      const int cc = sc ^ (row & 3);
      gload16(A + (size_t)(m0 + row) * EE + k0 + cc * 8,
              (char*)As + q * 4096 + wv * 1024);
      gload16(Bt + (size_t)(n0 + row) * EE + k0 + cc * 8,
              (char*)Bs + q * 4096 + wv * 1024);
    }
    __syncthreads();
    f16x8 af[4], bf[4];
#pragma unroll
    for (int mi = 0; mi < 4; ++mi) {
      const int row = wm * 64 + mi * 16 + r;
      af[mi] = *(const f16x8*)&As[row * 32 + ((kb ^ (row & 3)) * 8)];
    }
#pragma unroll
    for (int ni = 0; ni < 4; ++ni) {
      const int row = wn * 64 + ni * 16 + r;
      bf[ni] = *(const f16x8*)&Bs[row * 32 + ((kb ^ (row & 3)) * 8)];
    }
#pragma unroll
    for (int mi = 0; mi < 4; ++mi)
#pragma unroll
      for (int ni = 0; ni < 4; ++ni)
        acc[mi][ni] = __builtin_amdgcn_mfma_f32_16x16x32_f16(af[mi], bf[ni], acc[mi][ni], 0, 0, 0);
  }
  const int rb = kb * 4;
#pragma unroll
  for (int mi = 0; mi < 4; ++mi)
#pragma unroll
    for (int ni = 0; ni < 4; ++ni)
#pragma unroll
      for (int j = 0; j < 4; ++j) {
        const int m = m0 + wm * 64 + mi * 16 + rb + j;   // token index (b*512 + t)
        const int n = n0 + wn * 64 + ni * 16 + r;
        const int b = m >> 9, t = m & 511;
        __builtin_nontemporal_store(acc[mi][ni][j], &U[(size_t)(t * BB + b) * RR + n]);
      }
}

// ---------------- the sequential reservoir scan ----------------
// 4 batch-groups x 64 col-WGs, group pinned to XCD pair {2g,2g+1}.
// 9 waves/WG: 8 workers + 1 service. Service wave (leader WGs only) does the
// per-XCD L2 invalidate BETWEEN barrier-1 and barrier-2 of each step — at
// barrier-1 the workers' rotated octet polls have collectively confirmed all
// 64 group flags >= tau-1, which is exactly the fence-safety condition — and
// publishes fflag[xcd]=tau+1 well before any consumer's step-(tau+1) check.
// Workers: fflag load overlapped under a double-buffered (vmcnt(1)) octet
// poll; A-loads sc0 (L1 bypass, L2 served); stores write-through.

__launch_bounds__(576, 1)
__global__ void scan_kernel(const float* __restrict__ R, const float* __restrict__ U,
                            f16* __restrict__ S, unsigned* __restrict__ flg,
                            unsigned* __restrict__ fflag) {
  __shared__ __align__(16) char ldsbuf[CPW * RR * 2 + 16 * 1040];  // 128K Rt + reduce buf
  f16* Rt = (f16*)ldsbuf;
  const char* RtB = (const char*)ldsbuf;

  const int wg = blockIdx.x;
  const int xcd = wg & 7;                        // blockIdx%8 == XCD heuristic
  const int grp = xcd >> 1;                      // group on XCD pair
  const int cw = ((wg >> 3) << 1) | (wg & 1);    // 0..63 within group
  const bool leader = (wg >> 3) == 0;            // one leader WG per XCD
  const int nbase = cw * CPW;
  const int rbase = grp * RPG;
  const int tid = threadIdx.x;
  const int wv = tid >> 6, l = tid & 63;
  unsigned* gflags = flg + grp * 64 * FPAD;      // padded group flags
  unsigned* myflag = gflags + cw * FPAD;
  unsigned* myff = fflag + xcd * FPAD;

  // tau = 1: state_1 = tanh(u_0) on own 16x32 patch; publish early
  const int mm = tid >> 5, cc = tid & 31;        // row-in-group, col-in-slice
  if (tid < 512)
    storeS(&S[(size_t)(BB * RR) + (size_t)(rbase + mm) * RR + nbase + cc],
           fast_tanh(U[(size_t)(rbase + mm) * RR + nbase + cc]));
  __syncthreads();
  if (tid == 0) flag_st(myflag, 1u);

  // R column slice -> LDS (chunked conflict-free layout), once
  if (tid < 512) {
    const int c = tid & 31, kst = tid >> 5;
    for (int k = kst; k < RR; k += 16) {
      const float v = R[(size_t)k * RR + nbase + c];
      const int idx = ((k >> 5) << 10) + ((c >> 4) << 9) +
                      (((c & 15) << 2) + ((k >> 3) & 3)) * 8 + (k & 7);
      Rt[idx] = (f16)v;
    }
  }
  __syncthreads();

  if (wv < 8) {
    // ---------------- worker waves ----------------
    const int r = l & 15, kb = l >> 4;
    const int kblk = (wv + cw) & 7;          // k-rotation: stagger producer demand
    const unsigned voffA = (unsigned)((((rbase + r) * RR) + (kblk << 8) + kb * 8) * 2);
    const int bb0 = (r * 4 + kb) * 16;       // byte within 1024B chunk row
    const unsigned poff = (unsigned)(((grp * 64 + kblk * 8 + (l & 7)) * FPAD) * 4);
    const unsigned foff = (unsigned)((xcd * FPAD) * 4);
    // reduce-read coords for this thread's output element (mm, cc)
    const int ntr = cc >> 4;
    const int lred = (cc & 15) | ((mm >> 2) << 4);
    const int jred = mm & 3;

    f16x8 abuf[8];

    for (int tau = 2; tau <= TT; ++tau) {
      const f16* sprev = S + (size_t)((tau - 1) & 1) * (BB * RR);
      f16* snext = S + (size_t)(tau & 1) * (BB * RR);
      const unsigned need = (unsigned)(tau - 1);

      // fflag load first (checked AFTER the octet poll; RTT hides under it)
      unsigned ffv = bypass_ld(foff, fflag);
      // double-buffered octet poll: two loads in flight, vmcnt(1) alternation
      unsigned pv0 = bypass_ld(poff, flg);
      unsigned pv1 = bypass_ld(poff, flg);
      for (;;) {
        wait_vm<1>();                           // retires (ffv,) pv0
        if (__all(pv0 >= need)) break;
        pv0 = bypass_ld(poff, flg);
        wait_vm<1>();                           // retires pv1
        if (__all(pv1 >= need)) break;
        pv1 = bypass_ld(poff, flg);
        __builtin_amdgcn_s_sleep(0);
      }
      wait_vm<0>();                             // drain leftover poll loads
      // confirm this XCD's invalidate covers step tau (usually pre-satisfied)
      while (ffv < (unsigned)tau) {
        __builtin_amdgcn_s_sleep(1);
        ffv = flag_ld(myff);
      }

      // issue 8 sc0 A-loads, then the U element (oldest->newest: A0..A7, U)
      issue8(abuf, voffA, sprev);
      const float uval = __builtin_nontemporal_load(
          &U[(size_t)(tau - 1) * (BB * RR) + (size_t)(rbase + mm) * RR + nbase + cc]);

      f32x4 acc0 = {0.f, 0.f, 0.f, 0.f}, acc1 = {0.f, 0.f, 0.f, 0.f};
#define KSTEP(ks)                                                              \
  {                                                                            \
    const int kc = (kblk << 3) + (ks);                                         \
    f16x8 b0 = *(const f16x8*)(RtB + kc * 2048 + bb0);                         \
    f16x8 b1 = *(const f16x8*)(RtB + kc * 2048 + 1024 + bb0);                  \
    acc0 = __builtin_amdgcn_mfma_f32_16x16x32_f16(abuf[ks], b0, acc0, 0, 0, 0);\
    acc1 = __builtin_amdgcn_mfma_f32_16x16x32_f16(abuf[ks], b1, acc1, 0, 0, 0);\
  }
      wait_vm<5>();                             // A0..A3 ready (U still out)
      KSTEP(0) KSTEP(1) KSTEP(2) KSTEP(3)
      wait_vm<1>();                             // A4..A7 ready (U still out)
      KSTEP(4) KSTEP(5) KSTEP(6) KSTEP(7)
#undef KSTEP

      // partial accumulators -> LDS (padded per-wave copies), 8-way reduce
      {
        char* red = ldsbuf + CPW * RR * 2;
        *(f32x4*)(red + (wv * 2 + 0) * 1040 + l * 16) = acc0;
        *(f32x4*)(red + (wv * 2 + 1) * 1040 + l * 16) = acc1;
      }
      __syncthreads();                          // barrier-1
      {
        const char* red = ldsbuf + CPW * RR * 2;
        float s = 0.f;
#pragma unroll
        for (int w = 0; w < 8; ++w)
          s += *(const float*)(red + (w * 2 + ntr) * 1040 + lred * 16 + jred * 4);
        storeS(&snext[(size_t)(rbase + mm) * RR + nbase + cc], fast_tanh(s + uval));
      }
      __syncthreads();                          // barrier-2 (drains stores)
      if (tid == 0) flag_st(myflag, (unsigned)tau);
    }
  } else {
    // ---------------- service wave (wv == 8) ----------------
    // prologue fence: clears previous-replay L2 lines before step-2 loads
    if (leader) {
      __builtin_amdgcn_fence(__ATOMIC_ACQUIRE, "agent");
      if (l == 0) flag_st(myff, 2u);
    }
    for (int tau = 2; tau <= TT; ++tau) {
      __syncthreads();                          // barrier-1
      // at barrier-1 the 8 worker waves' rotated octet polls have confirmed
      // ALL 64 group flags >= tau-1  ==>  all same-XCD step-(tau-1) reads done
      if (leader && tau < TT) {
        __builtin_amdgcn_fence(__ATOMIC_ACQUIRE, "agent");
        if (l == 0) flag_st(myff, (unsigned)(tau + 1));
      }
      __syncthreads();                          // barrier-2
    }
  }
}

// ---------------- LayerNorm ----------------

__launch_bounds__(256, 1)
__global__ void ln_kernel(const f16* __restrict__ Sfin, const float* __restrict__ gamma,
                          const float* __restrict__ beta, float* __restrict__ out) {
  const int b = blockIdx.x;
  const int tid = threadIdx.x;
  const f16* row = Sfin + (size_t)b * RR;
  float vals[8];
  float lsum = 0.f, lsq = 0.f;
#pragma unroll
  for (int i = 0; i < 8; ++i) {
    float v = (float)row[tid + i * 256];
    vals[i] = v; lsum += v; lsq += v * v;
  }
#pragma unroll
  for (int off = 32; off >= 1; off >>= 1) {
    lsum += __shfl_xor(lsum, off);
    lsq  += __shfl_xor(lsq, off);
  }
  __shared__ float ps[4], pq[4];
  __shared__ float mu_s, rstd_s;
  const int wv = tid >> 6, l = tid & 63;
  if (l == 0) { ps[wv] = lsum; pq[wv] = lsq; }
  __syncthreads();
  if (tid == 0) {
    float s = 0.f, q = 0.f;
    for (int i = 0; i < 4; ++i) { s += ps[i]; q += pq[i]; }
    const float mu = s / RR;
    const float var = q / RR - mu * mu;
    mu_s = mu; rstd_s = rsqrtf(var + 1e-5f);
  }
  __syncthreads();
  const float mu = mu_s, rstd = rstd_s;
#pragma unroll
  for (int i = 0; i < 8; ++i) {
    const int idx = tid + i * 256;
    out[(size_t)b * RR + idx] = (vals[i] - mu) * rstd * gamma[idx] + beta[idx];
  }
}

// ---------------- launch ----------------

extern "C" void kernel_launch(void* const* d_in, const int* in_sizes, int n_in,
                              void* d_out, int out_size, void* d_ws, size_t ws_size,
                              hipStream_t stream) {
  const int*   x     = (const int*)d_in[0];
  const float* ew    = (const float*)d_in[1];
  const float* Rm    = (const float*)d_in[2];
  const float* Win   = (const float*)d_in[3];
  const float* gamma = (const float*)d_in[4];
  const float* beta  = (const float*)d_in[5];

  const size_t U_OFF   = 0;                           // fp32  512*64*2048*4
  const size_t EMB_OFF = 268435456;                   // fp16  32768*512*2
  const size_t WT_OFF  = EMB_OFF + 33554432;          // fp16  2048*512*2
  const size_t S_OFF   = WT_OFF + 2097152;            // fp16  2*64*2048*2
  const size_t BAR_OFF = S_OFF + 524288;              // u32   256 flags x 64B
  const size_t FF_OFF  = BAR_OFF + 16384;             // u32   8 x 64B
  const size_t NEED    = FF_OFF + 1024;
  if (ws_size < NEED) {
    hipMemsetAsync(d_out, 0, (size_t)out_size * 4, stream);
    return;
  }
  char* ws = (char*)d_ws;
  float*    Ubuf  = (float*)(ws + U_OFF);
  f16*      emb   = (f16*)(ws + EMB_OFF);
  f16*      WinT  = (f16*)(ws + WT_OFF);
  f16*      Sbuf  = (f16*)(ws + S_OFF);
  unsigned* flg   = (unsigned*)(ws + BAR_OFF);
  unsigned* fflag = (unsigned*)(ws + FF_OFF);

  hipMemsetAsync(flg, 0, 16384 + 1024, stream);   // group flags + fence flags
  prep_emb<<<BB * TT, 128, 0, stream>>>(x, ew, emb);
  prep_winT<<<(EE * RR) / 256, 256, 0, stream>>>(Win, WinT);
  proj_gemm<<<dim3((BB * TT) / 128, RR / 128), 256, 0, stream>>>(emb, WinT, Ubuf);
  scan_kernel<<<NWGS, 576, 0, stream>>>(Rm, Ubuf, Sbuf, flg, fflag);
  // state_512 lives at instance 512&1 == 0
  ln_kernel<<<BB, 256, 0, stream>>>(Sbuf, gamma, beta, (float*)d_out);
}